// Round 4
// baseline (807.597 us; speedup 1.0000x reference)
//
#include <hip/hip_runtime.h>

#define DM 1024
#define NHEADS 16
#define DK 64
#define BSZ 2
#define NSEQ 8192
#define MROWS (BSZ*NSEQ)
#define NCHUNKS 16
#define CHUNKN 512

typedef unsigned short u16;
typedef __attribute__((ext_vector_type(8))) short short8;
typedef __attribute__((ext_vector_type(4))) float f32x4;
typedef __attribute__((ext_vector_type(16))) float f32x16;

constexpr float EPS_F = 1e-6f;

__device__ __forceinline__ u16 f2bf(float x) {
  union { float f; unsigned u; } c; c.f = x;
  unsigned r = c.u + 0x7FFFu + ((c.u >> 16) & 1u);
  return (u16)(r >> 16);
}
__device__ __forceinline__ float bf2f(u16 h) {
  union { unsigned u; float f; } c; c.u = ((unsigned)h) << 16;
  return c.f;
}

typedef __attribute__((address_space(1))) const void gvoid_t;
typedef __attribute__((address_space(3))) void lvoid_t;
__device__ __forceinline__ void gl2lds16(const void* g, void* l) {
  // width=16: global_load_lds_dwordx4; LDS dst = wave-uniform base + lane*16
  __builtin_amdgcn_global_load_lds((gvoid_t*)g, (lvoid_t*)l, 16, 0, 0);
}

// fp32 -> (hi bf16, lo bf16) split.  hi = rne(x), lo = rne(x - hi).
__global__ __launch_bounds__(256)
void split_kernel(const float* __restrict__ src, u16* __restrict__ hi,
                  u16* __restrict__ lo, int n4) {
  int i = blockIdx.x * 256 + threadIdx.x;
  const int stride = gridDim.x * 256;
  for (; i < n4; i += stride) {
    const float4 v = ((const float4*)src)[i];
    const u16 h0 = f2bf(v.x), h1 = f2bf(v.y), h2 = f2bf(v.z), h3 = f2bf(v.w);
    const u16 l0 = f2bf(v.x - bf2f(h0)), l1 = f2bf(v.y - bf2f(h1));
    const u16 l2 = f2bf(v.z - bf2f(h2)), l3 = f2bf(v.w - bf2f(h3));
    ((ushort4*)hi)[i] = make_ushort4(h0, h1, h2, h3);
    ((ushort4*)lo)[i] = make_ushort4(l0, l1, l2, l3);
  }
}

// All four 1024x1024 weights split in one launch (cuts 3 launch gaps).
__global__ __launch_bounds__(256)
void wsplit_kernel(const float* __restrict__ w0, const float* __restrict__ w1,
                   const float* __restrict__ w2, const float* __restrict__ w3,
                   u16* __restrict__ h0, u16* __restrict__ l0,
                   u16* __restrict__ h1, u16* __restrict__ l1,
                   u16* __restrict__ h2, u16* __restrict__ l2,
                   u16* __restrict__ h3, u16* __restrict__ l3) {
  constexpr int per = DM * DM / 4;   // 2^18 float4s per weight
  int i = blockIdx.x * 256 + threadIdx.x;
  const int stride = gridDim.x * 256;
  for (; i < 4 * per; i += stride) {
    const int w = i >> 18, j = i & (per - 1);
    const float* src = w == 0 ? w0 : w == 1 ? w1 : w == 2 ? w2 : w3;
    u16* hi = w == 0 ? h0 : w == 1 ? h1 : w == 2 ? h2 : h3;
    u16* lo = w == 0 ? l0 : w == 1 ? l1 : w == 2 ? l2 : l3;
    const float4 v = ((const float4*)src)[j];
    const u16 a0 = f2bf(v.x), a1 = f2bf(v.y), a2 = f2bf(v.z), a3 = f2bf(v.w);
    ((ushort4*)hi)[j] = make_ushort4(a0, a1, a2, a3);
    ((ushort4*)lo)[j] = make_ushort4(f2bf(v.x - bf2f(a0)), f2bf(v.y - bf2f(a1)),
                                     f2bf(v.z - bf2f(a2)), f2bf(v.w - bf2f(a3)));
  }
}

// C[M x N] = (Ahi+Alo)[M x K] @ (Whi+Wlo)[N x K]^T + bias via 3 bf16 MFMA
// passes (hi*hi + hi*lo + lo*hi).  128x128 tile, BK=32, 4 waves 2x2, each
// wave 64x64 = 2x2 tiles of 32x32x16 MFMA (2382 TF shape vs 2075 for 16x16).
// MODE: 0 = f32 normal, 1 = bf16 normal, 2 = bf16 transposed (C^T[N][M]),
//       3 = bf16 transposed + ksum column-sum atomics (for K projection).
template<int ACT, int MODE>
__global__ __launch_bounds__(256)
void gemm_mfma_kernel(const u16* __restrict__ Ahi, const u16* __restrict__ Alo,
                      const u16* __restrict__ Whi, const u16* __restrict__ Wlo,
                      const float* __restrict__ bias, void* __restrict__ Cout,
                      float* __restrict__ ksum) {
  constexpr int K = DM, N = DM, BK = 32;
  __shared__ u16 Ash[128 * BK], Asl[128 * BK], Wsh[128 * BK], Wsl[128 * BK];
  const int tid = threadIdx.x;
  const int lane = tid & 63, wv = tid >> 6;
  const int bRow = blockIdx.y * 128, bCol = blockIdx.x * 128;

  // staging: slot s in [0,512) covers tile row s>>2, k-offset (s&3)*8;
  // LDS elem offset s*8 == row*BK + koff (row-major [128][BK]).
  const int s0 = wv * 128 + lane;
  const int s1 = s0 + 64;
  const int r0 = s0 >> 2, c0 = (s0 & 3) * 8;
  const int r1 = s1 >> 2, c1 = (s1 & 3) * 8;
  const u16* gAh0 = Ahi + (size_t)(bRow + r0) * K + c0;
  const u16* gAh1 = Ahi + (size_t)(bRow + r1) * K + c1;
  const u16* gAl0 = Alo + (size_t)(bRow + r0) * K + c0;
  const u16* gAl1 = Alo + (size_t)(bRow + r1) * K + c1;
  const u16* gWh0 = Whi + (size_t)(bCol + r0) * K + c0;
  const u16* gWh1 = Whi + (size_t)(bCol + r1) * K + c1;
  const u16* gWl0 = Wlo + (size_t)(bCol + r0) * K + c0;
  const u16* gWl1 = Wlo + (size_t)(bCol + r1) * K + c1;
  u16* const lA0 = Ash + (wv * 2 + 0) * 512;
  u16* const lA1 = Ash + (wv * 2 + 1) * 512;
  u16* const lB0 = Asl + (wv * 2 + 0) * 512;
  u16* const lB1 = Asl + (wv * 2 + 1) * 512;
  u16* const lC0 = Wsh + (wv * 2 + 0) * 512;
  u16* const lC1 = Wsh + (wv * 2 + 1) * 512;
  u16* const lD0 = Wsl + (wv * 2 + 0) * 512;
  u16* const lD1 = Wsl + (wv * 2 + 1) * 512;

  const int wm = (wv & 1) * 64, wn = (wv >> 1) * 64;
  // 32x32x16 A/B fragment: row/col = lane&31, k = (lane>>5)*8 + j
  const int fr = lane & 31, fk = (lane >> 5) * 8;

  f32x16 acc[2][2] = {};

  for (int k0 = 0; k0 < K; k0 += BK) {
    gl2lds16(gAh0 + k0, lA0); gl2lds16(gAh1 + k0, lA1);
    gl2lds16(gAl0 + k0, lB0); gl2lds16(gAl1 + k0, lB1);
    gl2lds16(gWh0 + k0, lC0); gl2lds16(gWh1 + k0, lC1);
    gl2lds16(gWl0 + k0, lD0); gl2lds16(gWl1 + k0, lD1);
    __syncthreads();

    short8 ah[2][2], al[2][2], bh[2][2], bl[2][2];   // [tile][kstep]
#pragma unroll
    for (int mt = 0; mt < 2; mt++)
#pragma unroll
      for (int ks = 0; ks < 2; ks++) {
        ah[mt][ks] = *(const short8*)(Ash + (wm + mt * 32 + fr) * BK + ks * 16 + fk);
        al[mt][ks] = *(const short8*)(Asl + (wm + mt * 32 + fr) * BK + ks * 16 + fk);
      }
#pragma unroll
    for (int nt = 0; nt < 2; nt++)
#pragma unroll
      for (int ks = 0; ks < 2; ks++) {
        bh[nt][ks] = *(const short8*)(Wsh + (wn + nt * 32 + fr) * BK + ks * 16 + fk);
        bl[nt][ks] = *(const short8*)(Wsl + (wn + nt * 32 + fr) * BK + ks * 16 + fk);
      }
#pragma unroll
    for (int ks = 0; ks < 2; ks++)
#pragma unroll
      for (int mt = 0; mt < 2; mt++)
#pragma unroll
        for (int nt = 0; nt < 2; nt++) {
          acc[mt][nt] = __builtin_amdgcn_mfma_f32_32x32x16_bf16(ah[mt][ks], bh[nt][ks], acc[mt][nt], 0, 0, 0);
          acc[mt][nt] = __builtin_amdgcn_mfma_f32_32x32x16_bf16(ah[mt][ks], bl[nt][ks], acc[mt][nt], 0, 0, 0);
          acc[mt][nt] = __builtin_amdgcn_mfma_f32_32x32x16_bf16(al[mt][ks], bh[nt][ks], acc[mt][nt], 0, 0, 0);
        }
    __syncthreads();
  }

  // 32x32 C/D layout: col = lane&31, row = (reg&3) + 8*(reg>>2) + 4*(lane>>5)
  const int rhalf = (lane >> 5) * 4;
  const int ec = lane & 31;
  float bv[2];
#pragma unroll
  for (int nt = 0; nt < 2; nt++) bv[nt] = bias[bCol + wn + nt * 32 + ec];
  float csum[2] = {0.f, 0.f};
#pragma unroll
  for (int mt = 0; mt < 2; mt++)
#pragma unroll
    for (int nt = 0; nt < 2; nt++) {
      if (MODE >= 2) {
        const size_t colg = (size_t)(bCol + wn + nt * 32 + ec);
#pragma unroll
        for (int q = 0; q < 4; q++) {
          ushort4 o4;
          u16* o = (u16*)&o4;
#pragma unroll
          for (int rr = 0; rr < 4; rr++) {
            float v = acc[mt][nt][q * 4 + rr] + bv[nt];
            if (ACT) v = v > 0.f ? (v + 1.f) : __expf(v);
            if (MODE == 3) csum[nt] += v;
            o[rr] = f2bf(v);
          }
          const size_t rowb = (size_t)bRow + wm + mt * 32 + 8 * q + rhalf;
          *(ushort4*)((u16*)Cout + colg * MROWS + rowb) = o4;
        }
      } else {
#pragma unroll
        for (int r = 0; r < 16; r++) {
          const size_t row = (size_t)bRow + wm + mt * 32 + (r & 3) + 8 * (r >> 2) + rhalf;
          const size_t col = (size_t)bCol + wn + nt * 32 + ec;
          float v = acc[mt][nt][r] + bv[nt];
          if (ACT) v = v > 0.f ? (v + 1.f) : __expf(v);
          if (MODE == 0) ((float*)Cout)[row * N + col] = v;
          else           ((u16*)Cout)[row * N + col] = f2bf(v);
        }
      }
    }
  if (MODE == 3) {
    const int bidx = bRow >> 13;  // batch index of this 128-row strip
#pragma unroll
    for (int nt = 0; nt < 2; nt++) {
      float s = csum[nt];
      s += __shfl_xor(s, 32, 64);   // combine the two row-halves (same col)
      if (lane < 32)
        atomicAdd(&ksum[bidx * DM + bCol + wn + nt * 32 + lane], s);
    }
  }
}

// KVT[m][d] partial = sum_n vT[m][n]*kT[d][n] over this block's 512-n chunk.
__global__ __launch_bounds__(256)
void kv_mfma_kernel(const u16* __restrict__ kT, const u16* __restrict__ vT,
                    float* __restrict__ part) {
  const int bh = blockIdx.y;
  const int b = bh >> 4, h = bh & 15;
  const size_t colbase = (size_t)b * NSEQ + blockIdx.x * CHUNKN;
  __shared__ u16 kts[64 * 64], vts[64 * 64];
  const int tid = threadIdx.x, lane = tid & 63, w = tid >> 6;
  const int wm = (w & 1) * 32, wd = (w >> 1) * 32;
  const int fr = lane & 15, fk = (lane >> 4) * 8;
  const int srow = lane >> 3, scol = (lane & 7) * 8;

  f32x4 acc[2][2] = {};

  for (int s = 0; s < CHUNKN / 64; s++) {
    const size_t cb = colbase + s * 64 + scol;
#pragma unroll
    for (int i = 0; i < 2; i++) {
      const int ii = w * 2 + i;
      const size_t grow = (size_t)(h * DK + ii * 8 + srow) * MROWS + cb;
      gl2lds16(vT + grow, vts + ii * 512);
      gl2lds16(kT + grow, kts + ii * 512);
    }
    __syncthreads();
#pragma unroll
    for (int ks = 0; ks < 2; ks++) {
      short8 af[2], bfr[2];
#pragma unroll
      for (int mt = 0; mt < 2; mt++)
        af[mt] = *(const short8*)(vts + (wm + mt * 16 + fr) * 64 + ks * 32 + fk);
#pragma unroll
      for (int dt = 0; dt < 2; dt++)
        bfr[dt] = *(const short8*)(kts + (wd + dt * 16 + fr) * 64 + ks * 32 + fk);
#pragma unroll
      for (int mt = 0; mt < 2; mt++)
#pragma unroll
        for (int dt = 0; dt < 2; dt++)
          acc[mt][dt] = __builtin_amdgcn_mfma_f32_16x16x32_bf16(af[mt], bfr[dt], acc[mt][dt], 0, 0, 0);
    }
    __syncthreads();
  }

  float* pp = part + ((size_t)blockIdx.x * 32 + bh) * (DK * DK);
  const int erow = (lane >> 4) * 4, ecol = lane & 15;
#pragma unroll
  for (int mt = 0; mt < 2; mt++)
#pragma unroll
    for (int dt = 0; dt < 2; dt++)
#pragma unroll
      for (int r = 0; r < 4; r++)
        pp[(wm + mt * 16 + erow + r) * DK + wd + dt * 16 + ecol] = acc[mt][dt][r];
}

// Reduce the 16 chunk-partials -> bf16 KVT[bh][m][d].
__global__ __launch_bounds__(256)
void kvt_reduce_kernel(const float* __restrict__ part, u16* __restrict__ kvt) {
  const int bh = blockIdx.x, t = threadIdx.x;
  const int i0 = t * 16;
  f32x4 s[4] = {};
  for (int c = 0; c < NCHUNKS; c++) {
    const f32x4* p = (const f32x4*)(part + ((size_t)c * 32 + bh) * (DK * DK) + i0);
#pragma unroll
    for (int q = 0; q < 4; q++) s[q] += p[q];
  }
  short8 o[2];
#pragma unroll
  for (int j = 0; j < 16; j++) o[j >> 3][j & 7] = (short)f2bf(s[j >> 2][j & 3]);
  *(short8*)(kvt + (size_t)bh * (DK * DK) + i0) = o[0];
  *(short8*)(kvt + (size_t)bh * (DK * DK) + i0 + 8) = o[1];
}

// out[n][m] = (q[n][:] . KVT[m][:]) / (q[n][:] . ksum + eps), per (b,h).
__global__ __launch_bounds__(256)
void attn_mfma_kernel(const u16* __restrict__ qp, const u16* __restrict__ kvt,
                      const float* __restrict__ ksum,
                      u16* __restrict__ ahi, u16* __restrict__ alo) {
  const int bh = blockIdx.y;
  const int b = bh >> 4, h = bh & 15;
  const int n0 = blockIdx.x * 128;
  const int tid = threadIdx.x, lane = tid & 63, w = tid >> 6;
  const int fr = lane & 15, fk = (lane >> 4) * 8;
  __shared__ float norm_lds[128];

  short8 bfr[4][2];
#pragma unroll
  for (int mt = 0; mt < 4; mt++)
#pragma unroll
    for (int ks = 0; ks < 2; ks++)
      bfr[mt][ks] = *(const short8*)(kvt + (size_t)bh * (DK * DK) + (mt * 16 + fr) * DK + ks * 32 + fk);

  float ksf[2][8];
#pragma unroll
  for (int ks = 0; ks < 2; ks++)
#pragma unroll
    for (int j = 0; j < 8; j++)
      ksf[ks][j] = ksum[b * DM + h * DK + ks * 32 + fk + j];

  const int nb = n0 + w * 32;
  short8 af[2][2];
#pragma unroll
  for (int nt = 0; nt < 2; nt++)
#pragma unroll
    for (int ks = 0; ks < 2; ks++)
      af[nt][ks] = *(const short8*)(qp + (size_t)(b * NSEQ + nb + nt * 16 + fr) * DM + h * DK + ks * 32 + fk);

  f32x4 acc[2][4] = {};
#pragma unroll
  for (int nt = 0; nt < 2; nt++)
#pragma unroll
    for (int mt = 0; mt < 4; mt++)
#pragma unroll
      for (int ks = 0; ks < 2; ks++)
        acc[nt][mt] = __builtin_amdgcn_mfma_f32_16x16x32_bf16(af[nt][ks], bfr[mt][ks], acc[nt][mt], 0, 0, 0);

#pragma unroll
  for (int nt = 0; nt < 2; nt++) {
    float p = 0.f;
#pragma unroll
    for (int ks = 0; ks < 2; ks++)
#pragma unroll
      for (int j = 0; j < 8; j++)
        p += bf2f((u16)af[nt][ks][j]) * ksf[ks][j];
    p += __shfl_xor(p, 16, 64);
    p += __shfl_xor(p, 32, 64);
    if ((lane >> 4) == 0) norm_lds[w * 32 + nt * 16 + fr] = p + EPS_F;
  }
  __syncthreads();

  const int erow = (lane >> 4) * 4, ec = lane & 15;
#pragma unroll
  for (int nt = 0; nt < 2; nt++) {
    float inv[4];
#pragma unroll
    for (int r = 0; r < 4; r++) inv[r] = 1.f / norm_lds[w * 32 + nt * 16 + erow + r];
#pragma unroll
    for (int mt = 0; mt < 4; mt++)
#pragma unroll
      for (int r = 0; r < 4; r++) {
        const float v = acc[nt][mt][r] * inv[r];
        const size_t o = (size_t)(b * NSEQ + nb + nt * 16 + erow + r) * DM + h * DK + mt * 16 + ec;
        const u16 hh = f2bf(v);
        ahi[o] = hh;
        alo[o] = f2bf(v - bf2f(hh));
      }
  }
}

extern "C" void kernel_launch(void* const* d_in, const int* in_sizes, int n_in,
                              void* d_out, int out_size, void* d_ws, size_t ws_size,
                              hipStream_t stream) {
  const float* query = (const float*)d_in[0];
  const float* key   = (const float*)d_in[1];
  const float* value = (const float*)d_in[2];
  const float* wq = (const float*)d_in[3];
  const float* bq = (const float*)d_in[4];
  const float* wk = (const float*)d_in[5];
  const float* bk = (const float*)d_in[6];
  const float* wv = (const float*)d_in[7];
  const float* bv = (const float*)d_in[8];
  const float* wo = (const float*)d_in[9];
  const float* bo = (const float*)d_in[10];
  float* out = (float*)d_out;

  constexpr size_t WELEM = (size_t)DM * DM;
  constexpr size_t AELEM = (size_t)MROWS * DM;

  char* p = (char*)d_ws;
  auto take = [&](size_t bytes) { char* q = p; p += (bytes + 255) & ~(size_t)255; return q; };
  u16* wqh = (u16*)take(WELEM * 2); u16* wql = (u16*)take(WELEM * 2);
  u16* wkh = (u16*)take(WELEM * 2); u16* wkl = (u16*)take(WELEM * 2);
  u16* wvh = (u16*)take(WELEM * 2); u16* wvl = (u16*)take(WELEM * 2);
  u16* woh = (u16*)take(WELEM * 2); u16* wol = (u16*)take(WELEM * 2);
  u16* chi = (u16*)take(AELEM * 2); u16* clo = (u16*)take(AELEM * 2);
  u16* qp  = (u16*)take(AELEM * 2);
  u16* kT  = (u16*)take(AELEM * 2);
  u16* vT  = (u16*)take(AELEM * 2);
  float* part = (float*)take((size_t)NCHUNKS * 32 * DK * DK * 4);
  float* ksum = (float*)take((size_t)BSZ * DM * 4);
  u16* kvt = (u16*)take((size_t)BSZ * NHEADS * DK * DK * 2);
  u16* ahi = chi; u16* alo = clo;   // chi/clo dead after V-GEMM reads them

  hipMemsetAsync(ksum, 0, (size_t)BSZ * DM * 4, stream);

  const dim3 blk(256);
  wsplit_kernel<<<1024, blk, 0, stream>>>(wq, wk, wv, wo, wqh, wql, wkh, wkl,
                                          wvh, wvl, woh, wol);

  const dim3 ggrid(DM / 128, MROWS / 128);
  split_kernel<<<2048, blk, 0, stream>>>(query, chi, clo, (int)(AELEM / 4));
  gemm_mfma_kernel<1, 1><<<ggrid, blk, 0, stream>>>(chi, clo, wqh, wql, bq, qp, nullptr);
  split_kernel<<<2048, blk, 0, stream>>>(key, chi, clo, (int)(AELEM / 4));
  gemm_mfma_kernel<1, 3><<<ggrid, blk, 0, stream>>>(chi, clo, wkh, wkl, bk, kT, ksum);
  split_kernel<<<2048, blk, 0, stream>>>(value, chi, clo, (int)(AELEM / 4));
  gemm_mfma_kernel<0, 2><<<ggrid, blk, 0, stream>>>(chi, clo, wvh, wvl, bv, vT, nullptr);

  kv_mfma_kernel<<<dim3(NCHUNKS, BSZ * NHEADS), blk, 0, stream>>>(kT, vT, part);
  kvt_reduce_kernel<<<32, blk, 0, stream>>>(part, kvt);
  attn_mfma_kernel<<<dim3(NSEQ / 128, BSZ * NHEADS), blk, 0, stream>>>(qp, kvt, ksum, ahi, alo);
  gemm_mfma_kernel<0, 0><<<ggrid, blk, 0, stream>>>(ahi, alo, woh, wol, bo, out, nullptr);
}

// Round 5
// 706.985 us; speedup vs baseline: 1.1423x; 1.1423x over previous
//
#include <hip/hip_runtime.h>

#define DM 1024
#define NHEADS 16
#define DK 64
#define BSZ 2
#define NSEQ 8192
#define MROWS (BSZ*NSEQ)
#define NCHUNKS 16
#define CHUNKN 512

typedef unsigned short u16;
typedef __attribute__((ext_vector_type(8))) short short8;
typedef __attribute__((ext_vector_type(4))) float f32x4;

constexpr float EPS_F = 1e-6f;

__device__ __forceinline__ u16 f2bf(float x) {
  union { float f; unsigned u; } c; c.f = x;
  unsigned r = c.u + 0x7FFFu + ((c.u >> 16) & 1u);
  return (u16)(r >> 16);
}
__device__ __forceinline__ float bf2f(u16 h) {
  union { unsigned u; float f; } c; c.u = ((unsigned)h) << 16;
  return c.f;
}

typedef __attribute__((address_space(1))) const void gvoid_t;
typedef __attribute__((address_space(3))) void lvoid_t;
__device__ __forceinline__ void gl2lds16(const void* g, void* l) {
  // width=16: global_load_lds_dwordx4; LDS dst = wave-uniform base + lane*16
  __builtin_amdgcn_global_load_lds((gvoid_t*)g, (lvoid_t*)l, 16, 0, 0);
}

// fp32 -> (hi bf16, lo bf16) split.  hi = rne(x), lo = rne(x - hi).
__global__ __launch_bounds__(256)
void split_kernel(const float* __restrict__ src, u16* __restrict__ hi,
                  u16* __restrict__ lo, int n4) {
  int i = blockIdx.x * 256 + threadIdx.x;
  const int stride = gridDim.x * 256;
  for (; i < n4; i += stride) {
    const float4 v = ((const float4*)src)[i];
    const u16 h0 = f2bf(v.x), h1 = f2bf(v.y), h2 = f2bf(v.z), h3 = f2bf(v.w);
    const u16 l0 = f2bf(v.x - bf2f(h0)), l1 = f2bf(v.y - bf2f(h1));
    const u16 l2 = f2bf(v.z - bf2f(h2)), l3 = f2bf(v.w - bf2f(h3));
    ((ushort4*)hi)[i] = make_ushort4(h0, h1, h2, h3);
    ((ushort4*)lo)[i] = make_ushort4(l0, l1, l2, l3);
  }
}

// All four 1024x1024 weights split in one launch; also zeroes ksum (2048 f32)
// so no separate memset node is needed.
__global__ __launch_bounds__(256)
void wsplit_kernel(const float* __restrict__ w0, const float* __restrict__ w1,
                   const float* __restrict__ w2, const float* __restrict__ w3,
                   u16* __restrict__ h0, u16* __restrict__ l0,
                   u16* __restrict__ h1, u16* __restrict__ l1,
                   u16* __restrict__ h2, u16* __restrict__ l2,
                   u16* __restrict__ h3, u16* __restrict__ l3,
                   float* __restrict__ ksum) {
  if (blockIdx.x < 8) ksum[blockIdx.x * 256 + threadIdx.x] = 0.f;
  constexpr int per = DM * DM / 4;   // 2^18 float4s per weight
  int i = blockIdx.x * 256 + threadIdx.x;
  const int stride = gridDim.x * 256;
  for (; i < 4 * per; i += stride) {
    const int w = i >> 18, j = i & (per - 1);
    const float* src = w == 0 ? w0 : w == 1 ? w1 : w == 2 ? w2 : w3;
    u16* hi = w == 0 ? h0 : w == 1 ? h1 : w == 2 ? h2 : h3;
    u16* lo = w == 0 ? l0 : w == 1 ? l1 : w == 2 ? l2 : l3;
    const float4 v = ((const float4*)src)[j];
    const u16 a0 = f2bf(v.x), a1 = f2bf(v.y), a2 = f2bf(v.z), a3 = f2bf(v.w);
    ((ushort4*)hi)[j] = make_ushort4(a0, a1, a2, a3);
    ((ushort4*)lo)[j] = make_ushort4(f2bf(v.x - bf2f(a0)), f2bf(v.y - bf2f(a1)),
                                     f2bf(v.z - bf2f(a2)), f2bf(v.w - bf2f(a3)));
  }
}

// C[M x N] = (Ahi+Alo)[M x K] @ (Whi+Wlo)[N x K]^T + bias via 3 bf16 MFMA
// passes (hi*hi + hi*lo + lo*hi).  128x128 tile, BK=32, 4 waves 2x2, each
// wave 64x64 = 4x4 tiles of 16x16x32 MFMA (the 32x32 shape regressed: 16-way
// LDS phase conflicts, r4).  XCD-aware block swizzle: the 8 column-blocks of
// one A-strip land on one XCD consecutively (A strip L2-resident; W set =
// 4 MB = one XCD L2).
// MODE: 0 = f32 normal, 1 = bf16 normal, 2 = bf16 transposed (C^T[N][M]),
//       3 = bf16 transposed + ksum column-sum atomics (for K projection).
template<int ACT, int MODE>
__global__ __launch_bounds__(256)
void gemm_mfma_kernel(const u16* __restrict__ Ahi, const u16* __restrict__ Alo,
                      const u16* __restrict__ Whi, const u16* __restrict__ Wlo,
                      const float* __restrict__ bias, void* __restrict__ Cout,
                      float* __restrict__ ksum) {
  constexpr int K = DM, N = DM, BK = 32;
  __shared__ u16 Ash[128 * BK], Asl[128 * BK], Wsh[128 * BK], Wsl[128 * BK];
  const int tid = threadIdx.x;
  const int lane = tid & 63, wv = tid >> 6;
  // swizzle: bits 3-5 -> col, bits 0-2 (xcd class) and 6-9 -> row
  const int bid = blockIdx.y * 8 + blockIdx.x;
  const int bx = (bid >> 3) & 7;
  const int by = ((bid & 7) << 4) | (bid >> 6);
  const int bRow = by * 128, bCol = bx * 128;

  // staging: slot s in [0,512) covers tile row s>>2, k-offset (s&3)*8;
  // LDS elem offset s*8 == row*BK + koff (row-major [128][BK]).
  const int s0 = wv * 128 + lane;
  const int s1 = s0 + 64;
  const int r0 = s0 >> 2, c0 = (s0 & 3) * 8;
  const int r1 = s1 >> 2, c1 = (s1 & 3) * 8;
  const u16* gAh0 = Ahi + (size_t)(bRow + r0) * K + c0;
  const u16* gAh1 = Ahi + (size_t)(bRow + r1) * K + c1;
  const u16* gAl0 = Alo + (size_t)(bRow + r0) * K + c0;
  const u16* gAl1 = Alo + (size_t)(bRow + r1) * K + c1;
  const u16* gWh0 = Whi + (size_t)(bCol + r0) * K + c0;
  const u16* gWh1 = Whi + (size_t)(bCol + r1) * K + c1;
  const u16* gWl0 = Wlo + (size_t)(bCol + r0) * K + c0;
  const u16* gWl1 = Wlo + (size_t)(bCol + r1) * K + c1;
  u16* const lA0 = Ash + (wv * 2 + 0) * 512;
  u16* const lA1 = Ash + (wv * 2 + 1) * 512;
  u16* const lB0 = Asl + (wv * 2 + 0) * 512;
  u16* const lB1 = Asl + (wv * 2 + 1) * 512;
  u16* const lC0 = Wsh + (wv * 2 + 0) * 512;
  u16* const lC1 = Wsh + (wv * 2 + 1) * 512;
  u16* const lD0 = Wsl + (wv * 2 + 0) * 512;
  u16* const lD1 = Wsl + (wv * 2 + 1) * 512;

  const int wm = (wv & 1) * 64, wn = (wv >> 1) * 64;
  const int fr = lane & 15, fk = (lane >> 4) * 8;

  f32x4 acc[4][4] = {};

  for (int k0 = 0; k0 < K; k0 += BK) {
    gl2lds16(gAh0 + k0, lA0); gl2lds16(gAh1 + k0, lA1);
    gl2lds16(gAl0 + k0, lB0); gl2lds16(gAl1 + k0, lB1);
    gl2lds16(gWh0 + k0, lC0); gl2lds16(gWh1 + k0, lC1);
    gl2lds16(gWl0 + k0, lD0); gl2lds16(gWl1 + k0, lD1);
    __syncthreads();

    short8 ah[4], al[4], bh[4], bl[4];
#pragma unroll
    for (int mt = 0; mt < 4; mt++) {
      ah[mt] = *(const short8*)(Ash + (wm + mt * 16 + fr) * BK + fk);
      al[mt] = *(const short8*)(Asl + (wm + mt * 16 + fr) * BK + fk);
    }
#pragma unroll
    for (int nt = 0; nt < 4; nt++) {
      bh[nt] = *(const short8*)(Wsh + (wn + nt * 16 + fr) * BK + fk);
      bl[nt] = *(const short8*)(Wsl + (wn + nt * 16 + fr) * BK + fk);
    }
#pragma unroll
    for (int mt = 0; mt < 4; mt++)
#pragma unroll
      for (int nt = 0; nt < 4; nt++) {
        acc[mt][nt] = __builtin_amdgcn_mfma_f32_16x16x32_bf16(ah[mt], bh[nt], acc[mt][nt], 0, 0, 0);
        acc[mt][nt] = __builtin_amdgcn_mfma_f32_16x16x32_bf16(ah[mt], bl[nt], acc[mt][nt], 0, 0, 0);
        acc[mt][nt] = __builtin_amdgcn_mfma_f32_16x16x32_bf16(al[mt], bh[nt], acc[mt][nt], 0, 0, 0);
      }
    __syncthreads();
  }

  // epilogue: C/D layout col = lane&15, row = (lane>>4)*4 + reg  [m89]
  const int erow = (lane >> 4) * 4;
  const int ecol = lane & 15;
  float bv[4];
#pragma unroll
  for (int nt = 0; nt < 4; nt++) bv[nt] = bias[bCol + wn + nt * 16 + ecol];
  float csum[4] = {0.f, 0.f, 0.f, 0.f};
#pragma unroll
  for (int mt = 0; mt < 4; mt++)
#pragma unroll
    for (int nt = 0; nt < 4; nt++)
#pragma unroll
      for (int r = 0; r < 4; r++) {
        const size_t row = (size_t)bRow + wm + mt * 16 + erow + r;
        const size_t col = (size_t)bCol + wn + nt * 16 + ecol;
        float v = acc[mt][nt][r] + bv[nt];
        if (ACT) v = v > 0.f ? (v + 1.f) : __expf(v);  // elu(x)+1
        if (MODE == 0)      ((float*)Cout)[row * N + col] = v;
        else if (MODE == 1) ((u16*)Cout)[row * N + col] = f2bf(v);
        else {
          ((u16*)Cout)[col * (size_t)MROWS + row] = f2bf(v);  // C^T
          if (MODE == 3) csum[nt] += v;
        }
      }
  if (MODE == 3) {
    const int bidx = bRow >> 13;  // which batch this 128-row strip is in
#pragma unroll
    for (int nt = 0; nt < 4; nt++) {
      float s = csum[nt];
      s += __shfl_xor(s, 16, 64);
      s += __shfl_xor(s, 32, 64);   // all quads now hold the 64-row column sum
      if ((lane >> 4) == 0)
        atomicAdd(&ksum[bidx * DM + bCol + wn + nt * 16 + ecol], s);
    }
  }
}

// KVT[m][d] partial = sum_n vT[m][n]*kT[d][n] over this block's 512-n chunk.
__global__ __launch_bounds__(256)
void kv_mfma_kernel(const u16* __restrict__ kT, const u16* __restrict__ vT,
                    float* __restrict__ part) {
  const int bh = blockIdx.y;
  const int b = bh >> 4, h = bh & 15;
  const size_t colbase = (size_t)b * NSEQ + blockIdx.x * CHUNKN;
  __shared__ u16 kts[64 * 64], vts[64 * 64];
  const int tid = threadIdx.x, lane = tid & 63, w = tid >> 6;
  const int wm = (w & 1) * 32, wd = (w >> 1) * 32;
  const int fr = lane & 15, fk = (lane >> 4) * 8;
  const int srow = lane >> 3, scol = (lane & 7) * 8;

  f32x4 acc[2][2] = {};

  for (int s = 0; s < CHUNKN / 64; s++) {
    const size_t cb = colbase + s * 64 + scol;
#pragma unroll
    for (int i = 0; i < 2; i++) {
      const int ii = w * 2 + i;
      const size_t grow = (size_t)(h * DK + ii * 8 + srow) * MROWS + cb;
      gl2lds16(vT + grow, vts + ii * 512);
      gl2lds16(kT + grow, kts + ii * 512);
    }
    __syncthreads();
#pragma unroll
    for (int ks = 0; ks < 2; ks++) {
      short8 af[2], bfr[2];
#pragma unroll
      for (int mt = 0; mt < 2; mt++)
        af[mt] = *(const short8*)(vts + (wm + mt * 16 + fr) * 64 + ks * 32 + fk);
#pragma unroll
      for (int dt = 0; dt < 2; dt++)
        bfr[dt] = *(const short8*)(kts + (wd + dt * 16 + fr) * 64 + ks * 32 + fk);
#pragma unroll
      for (int mt = 0; mt < 2; mt++)
#pragma unroll
        for (int dt = 0; dt < 2; dt++)
          acc[mt][dt] = __builtin_amdgcn_mfma_f32_16x16x32_bf16(af[mt], bfr[dt], acc[mt][dt], 0, 0, 0);
    }
    __syncthreads();
  }

  float* pp = part + ((size_t)blockIdx.x * 32 + bh) * (DK * DK);
  const int erow = (lane >> 4) * 4, ecol = lane & 15;
#pragma unroll
  for (int mt = 0; mt < 2; mt++)
#pragma unroll
    for (int dt = 0; dt < 2; dt++)
#pragma unroll
      for (int r = 0; r < 4; r++)
        pp[(wm + mt * 16 + erow + r) * DK + wd + dt * 16 + ecol] = acc[mt][dt][r];
}

// Reduce the 16 chunk-partials -> bf16 KVT[bh][m][d].
__global__ __launch_bounds__(256)
void kvt_reduce_kernel(const float* __restrict__ part, u16* __restrict__ kvt) {
  const int bh = blockIdx.x, t = threadIdx.x;
  const int i0 = t * 16;
  f32x4 s[4] = {};
  for (int c = 0; c < NCHUNKS; c++) {
    const f32x4* p = (const f32x4*)(part + ((size_t)c * 32 + bh) * (DK * DK) + i0);
#pragma unroll
    for (int q = 0; q < 4; q++) s[q] += p[q];
  }
  short8 o[2];
#pragma unroll
  for (int j = 0; j < 16; j++) o[j >> 3][j & 7] = (short)f2bf(s[j >> 2][j & 3]);
  *(short8*)(kvt + (size_t)bh * (DK * DK) + i0) = o[0];
  *(short8*)(kvt + (size_t)bh * (DK * DK) + i0 + 8) = o[1];
}

// out[n][m] = (q[n][:] . KVT[m][:]) / (q[n][:] . ksum + eps), per (b,h).
__global__ __launch_bounds__(256)
void attn_mfma_kernel(const u16* __restrict__ qp, const u16* __restrict__ kvt,
                      const float* __restrict__ ksum,
                      u16* __restrict__ ahi, u16* __restrict__ alo) {
  const int bh = blockIdx.y;
  const int b = bh >> 4, h = bh & 15;
  const int n0 = blockIdx.x * 128;
  const int tid = threadIdx.x, lane = tid & 63, w = tid >> 6;
  const int fr = lane & 15, fk = (lane >> 4) * 8;
  __shared__ float norm_lds[128];

  short8 bfr[4][2];
#pragma unroll
  for (int mt = 0; mt < 4; mt++)
#pragma unroll
    for (int ks = 0; ks < 2; ks++)
      bfr[mt][ks] = *(const short8*)(kvt + (size_t)bh * (DK * DK) + (mt * 16 + fr) * DK + ks * 32 + fk);

  float ksf[2][8];
#pragma unroll
  for (int ks = 0; ks < 2; ks++)
#pragma unroll
    for (int j = 0; j < 8; j++)
      ksf[ks][j] = ksum[b * DM + h * DK + ks * 32 + fk + j];

  const int nb = n0 + w * 32;
  short8 af[2][2];
#pragma unroll
  for (int nt = 0; nt < 2; nt++)
#pragma unroll
    for (int ks = 0; ks < 2; ks++)
      af[nt][ks] = *(const short8*)(qp + (size_t)(b * NSEQ + nb + nt * 16 + fr) * DM + h * DK + ks * 32 + fk);

  f32x4 acc[2][4] = {};
#pragma unroll
  for (int nt = 0; nt < 2; nt++)
#pragma unroll
    for (int mt = 0; mt < 4; mt++)
#pragma unroll
      for (int ks = 0; ks < 2; ks++)
        acc[nt][mt] = __builtin_amdgcn_mfma_f32_16x16x32_bf16(af[nt][ks], bfr[mt][ks], acc[nt][mt], 0, 0, 0);

#pragma unroll
  for (int nt = 0; nt < 2; nt++) {
    float p = 0.f;
#pragma unroll
    for (int ks = 0; ks < 2; ks++)
#pragma unroll
      for (int j = 0; j < 8; j++)
        p += bf2f((u16)af[nt][ks][j]) * ksf[ks][j];
    p += __shfl_xor(p, 16, 64);
    p += __shfl_xor(p, 32, 64);
    if ((lane >> 4) == 0) norm_lds[w * 32 + nt * 16 + fr] = p + EPS_F;
  }
  __syncthreads();

  const int erow = (lane >> 4) * 4, ec = lane & 15;
#pragma unroll
  for (int nt = 0; nt < 2; nt++) {
    float inv[4];
#pragma unroll
    for (int r = 0; r < 4; r++) inv[r] = 1.f / norm_lds[w * 32 + nt * 16 + erow + r];
#pragma unroll
    for (int mt = 0; mt < 4; mt++)
#pragma unroll
      for (int r = 0; r < 4; r++) {
        const float v = acc[nt][mt][r] * inv[r];
        const size_t o = (size_t)(b * NSEQ + nb + nt * 16 + erow + r) * DM + h * DK + mt * 16 + ec;
        const u16 hh = f2bf(v);
        ahi[o] = hh;
        alo[o] = f2bf(v - bf2f(hh));
      }
  }
}

extern "C" void kernel_launch(void* const* d_in, const int* in_sizes, int n_in,
                              void* d_out, int out_size, void* d_ws, size_t ws_size,
                              hipStream_t stream) {
  const float* query = (const float*)d_in[0];
  const float* key   = (const float*)d_in[1];
  const float* value = (const float*)d_in[2];
  const float* wq = (const float*)d_in[3];
  const float* bq = (const float*)d_in[4];
  const float* wk = (const float*)d_in[5];
  const float* bk = (const float*)d_in[6];
  const float* wv = (const float*)d_in[7];
  const float* bv = (const float*)d_in[8];
  const float* wo = (const float*)d_in[9];
  const float* bo = (const float*)d_in[10];
  float* out = (float*)d_out;

  constexpr size_t WELEM = (size_t)DM * DM;
  constexpr size_t AELEM = (size_t)MROWS * DM;

  char* p = (char*)d_ws;
  auto take = [&](size_t bytes) { char* q = p; p += (bytes + 255) & ~(size_t)255; return q; };
  u16* wqh = (u16*)take(WELEM * 2); u16* wql = (u16*)take(WELEM * 2);
  u16* wkh = (u16*)take(WELEM * 2); u16* wkl = (u16*)take(WELEM * 2);
  u16* wvh = (u16*)take(WELEM * 2); u16* wvl = (u16*)take(WELEM * 2);
  u16* woh = (u16*)take(WELEM * 2); u16* wol = (u16*)take(WELEM * 2);
  u16* chi = (u16*)take(AELEM * 2); u16* clo = (u16*)take(AELEM * 2);
  u16* qp  = (u16*)take(AELEM * 2);
  u16* kT  = (u16*)take(AELEM * 2);
  u16* vT  = (u16*)take(AELEM * 2);
  float* part = (float*)take((size_t)NCHUNKS * 32 * DK * DK * 4);
  float* ksum = (float*)take((size_t)BSZ * DM * 4);
  u16* kvt = (u16*)take((size_t)BSZ * NHEADS * DK * DK * 2);
  u16* ahi = chi; u16* alo = clo;   // chi/clo dead after V-GEMM reads them

  const dim3 blk(256);
  wsplit_kernel<<<1024, blk, 0, stream>>>(wq, wk, wv, wo, wqh, wql, wkh, wkl,
                                          wvh, wvl, woh, wol, ksum);

  const dim3 ggrid(DM / 128, MROWS / 128);
  split_kernel<<<2048, blk, 0, stream>>>(query, chi, clo, (int)(AELEM / 4));
  gemm_mfma_kernel<1, 1><<<ggrid, blk, 0, stream>>>(chi, clo, wqh, wql, bq, qp, nullptr);
  split_kernel<<<2048, blk, 0, stream>>>(key, chi, clo, (int)(AELEM / 4));
  gemm_mfma_kernel<1, 3><<<ggrid, blk, 0, stream>>>(chi, clo, wkh, wkl, bk, kT, ksum);
  split_kernel<<<2048, blk, 0, stream>>>(value, chi, clo, (int)(AELEM / 4));
  gemm_mfma_kernel<0, 2><<<ggrid, blk, 0, stream>>>(chi, clo, wvh, wvl, bv, vT, nullptr);

  kv_mfma_kernel<<<dim3(NCHUNKS, BSZ * NHEADS), blk, 0, stream>>>(kT, vT, part);
  kvt_reduce_kernel<<<32, blk, 0, stream>>>(part, kvt);
  attn_mfma_kernel<<<dim3(NSEQ / 128, BSZ * NHEADS), blk, 0, stream>>>(qp, kvt, ksum, ahi, alo);
  gemm_mfma_kernel<0, 0><<<ggrid, blk, 0, stream>>>(ahi, alo, woh, wol, bo, out, nullptr);
}